// Round 12
// baseline (506.050 us; speedup 1.0000x reference)
//
#include <hip/hip_runtime.h>

// Problem constants (fixed by reference)
constexpr int N_  = 10000;   // nodes (< 65536 -> u16 src)
constexpr int E_  = 320000;  // edges
constexpr int F1  = 33;      // input features
constexpr int H   = 32;      // hidden
constexpr int G   = 64;      // graphs
constexpr int CAP = 96;      // padded CSR slots/node (deg~Poisson(32), P(overflow)~1e-18/node)
constexpr int NB_ = 1280;    // node-blocks of 8 (covers 10240 >= N_)
constexpr int ROW = CAP * 8; // 768 dwords per node-block row in transposed meta

constexpr int EBLK = E_ / 256;   // 1250 edge blocks
constexpr int PBLK = N_ / 8;     // 1250 node-group tasks (8 nodes x 32 lanes)
constexpr int SLICES = 32;
constexpr int CHUNKS = 32;       // 1024 blocks; 40KB LDS -> 4 blocks/CU
constexpr int TILE   = 320;      // 32*320 = 10240 >= N_
constexpr int ITERS  = TILE / 32;

// round-to-nearest-even f32 -> bf16 (low 16 bits)
__device__ __forceinline__ unsigned bf16r(float x) {
    unsigned u = __float_as_uint(x);
    return (u + 0x7FFFu + ((u >> 16) & 1u)) >> 16;
}

// transposed meta slot address: node n, slot pos
__device__ __forceinline__ size_t mslot(int n, int pos) {
    return (size_t)(n >> 3) * ROW + (size_t)(pos >> 3) * 64 + (n & 7) * 8 + (pos & 7);
}

// ---------------- build: padded CSR (transposed) + layer-1 precompute ----------------

__global__ __launch_bounds__(256) void k_build_pre1(
        const int* __restrict__ ei, const float* __restrict__ ea,
        const float* __restrict__ x, const int* __restrict__ batch,
        const float* __restrict__ A, const float* __restrict__ Bm,
        const float* __restrict__ Rw, const float* __restrict__ bias,
        int* __restrict__ counts, unsigned* __restrict__ meta2,
        unsigned* __restrict__ UVs, float* __restrict__ Rs,
        int* __restrict__ startsP) {
    __shared__ unsigned s_uv[32][9];
    __shared__ float    s_r[32][9];
    if (blockIdx.x < EBLK) {
        int e = blockIdx.x * 256 + threadIdx.x;
        int s = ei[e];
        int d = ei[E_ + e];
        int pos = atomicAdd(&counts[d], 1);
        meta2[mslot(d, pos)] = (unsigned)s | (bf16r(ea[e]) << 16);
    } else {
        int base8 = (blockIdx.x - EBLK) * 8;
        int grp = threadIdx.x >> 5;
        int f = threadIdx.x & 31;
        int node = base8 + grp;
        if (f == 0) {   // graph-boundary detection (batch sorted)
            int b = batch[node];
            int bp = (node == 0) ? -1 : batch[node - 1];
            if (b != bp) startsP[b] = node + 1;
        }
        float u = 0.f, v = 0.f, r = bias[f];
        const float* xr = x + (size_t)node * F1;
        #pragma unroll
        for (int k = 0; k < F1; ++k) {
            float xv = xr[k];
            u = fmaf(xv, A[k * H + f], u);
            v = fmaf(xv, Bm[k * H + f], v);
            r = fmaf(xv, Rw[k * H + f], r);
        }
        s_uv[f][grp] = bf16r(u) | (bf16r(v) << 16);
        s_r[f][grp]  = r;
        __syncthreads();
        int fo = threadIdx.x >> 3;
        int nl = threadIdx.x & 7;
        UVs[(size_t)fo * N_ + base8 + nl] = s_uv[fo][nl];
        Rs [(size_t)fo * N_ + base8 + nl] = s_r [fo][nl];
    }
}

// ---------------- LDS-sliced conv agg + fused next-layer precompute (per-chunk ticket) ----
// block = (slice s, 320-node chunk). LDS = full per-feature UV table (40 KB).
// After the chunk's 32 slice-blocks finish, the LAST one (acq_rel ticket, agent scope)
// computes U,V,R of the NEXT layer for this chunk's nodes — no separate k_pre dispatch.

template<bool DO_PRE>
__global__ __launch_bounds__(256) void k_agg_lds(
        const int* __restrict__ counts, const unsigned* __restrict__ meta2,
        const unsigned* __restrict__ UVs, const float* __restrict__ Rs,
        float* __restrict__ Hs,
        const float* __restrict__ A2, const float* __restrict__ B2,
        const float* __restrict__ Rw2, const float* __restrict__ bi2,
        unsigned* __restrict__ UVo, float* __restrict__ Ro,
        unsigned* __restrict__ tickets) {
    __shared__ __align__(16) unsigned uvl[N_];
    int s     = blockIdx.x & 31;
    int chunk = blockIdx.x >> 5;

    int l   = threadIdx.x & 63;
    int wav = threadIdx.x >> 6;      // 0..3
    int j0  = l & 7;                 // slot within group
    int nl  = l >> 3;                // node within wave (0..7)

    // ---- initial prefetch (overlaps LDS fill) ----
    int cbase = chunk * TILE + wav * 8;
    int node = cbase + nl;
    int nc = min(node, N_ - 1);
    int dg = (node < N_) ? counts[nc] : 0;
    float rv = Rs[(size_t)s * N_ + nc];
    const unsigned* mrow = meta2 + (size_t)(cbase >> 3) * ROW + l;
    unsigned m0 = mrow[0], m1 = mrow[64], m2 = mrow[128],
             m3 = mrow[192], m4 = mrow[256], m5 = mrow[320];

    // ---- fill LDS with this slice's UV table (coalesced 40 KB) ----
    const unsigned* srcp = UVs + (size_t)s * N_;
    #pragma unroll
    for (int i = 0; i < 10; ++i) {
        int d4 = (i * 256 + threadIdx.x) * 4;
        if (d4 + 4 <= N_) {
            uint4 t = *reinterpret_cast<const uint4*>(srcp + d4);
            *reinterpret_cast<uint4*>(&uvl[d4]) = t;
        }
    }
    __syncthreads();

    for (int it = 0; it < ITERS; ++it) {
        // ---- prefetch next group ----
        int nbase = cbase + 32;
        int nnode = nbase + nl;
        int nnc = min(nnode, N_ - 1);
        int ndg = 0; float nrv = 0.f;
        unsigned n0 = 0, n1 = 0, n2 = 0, n3 = 0, n4 = 0, n5 = 0;
        if (it < ITERS - 1) {
            ndg = (nnode < N_) ? counts[nnc] : 0;
            nrv = Rs[(size_t)s * N_ + nnc];
            const unsigned* nmr = meta2 + (size_t)(nbase >> 3) * ROW + l;
            n0 = nmr[0]; n1 = nmr[64]; n2 = nmr[128];
            n3 = nmr[192]; n4 = nmr[256]; n5 = nmr[320];
        }

        // ---- compute current group ----
        int maxd = dg;
        maxd = max(maxd, __shfl_xor(maxd, 8));
        maxd = max(maxd, __shfl_xor(maxd, 16));
        maxd = max(maxd, __shfl_xor(maxd, 32));
        float acc = 0.f;
        auto slot = [&](int p, unsigned mv) {
            unsigned idx = min(mv & 0xFFFFu, (unsigned)(N_ - 1));
            unsigned w = uvl[idx];
            float t = fmaf(__uint_as_float(mv & 0xFFFF0000u),   // a (bf16 hi)
                           __uint_as_float(w << 16),            // u
                           __uint_as_float(w & 0xFFFF0000u));   // v
            if (j0 + 8 * p < dg) acc += t;
        };
        if (maxd > 0)  slot(0, m0);
        if (maxd > 8)  slot(1, m1);
        if (maxd > 16) slot(2, m2);
        if (maxd > 24) slot(3, m3);
        if (maxd > 32) slot(4, m4);
        if (maxd > 40) slot(5, m5);
        if (maxd > 48) {                       // rare tail
            const unsigned* trow = meta2 + (size_t)(cbase >> 3) * ROW + l;
            for (int p = 6; 8 * p < maxd; ++p)
                slot(p, trow[p * 64]);
        }
        acc += __shfl_xor(acc, 1);
        acc += __shfl_xor(acc, 2);
        acc += __shfl_xor(acc, 4);
        float h = fmaxf(rv + acc, 0.f);
        if (j0 == 0 && node < N_) Hs[(size_t)s * N_ + node] = h;

        cbase = nbase; node = nnode; nc = nnc; dg = ndg; rv = nrv;
        m0 = n0; m1 = n1; m2 = n2; m3 = n3; m4 = n4; m5 = n5;
    }

    if (DO_PRE) {
        __shared__ unsigned s_rank;
        __threadfence();             // release this block's Hs stores (device scope)
        __syncthreads();
        if (threadIdx.x == 0)
            s_rank = __hip_atomic_fetch_add(&tickets[chunk], 1u, __ATOMIC_ACQ_REL,
                                            __HIP_MEMORY_SCOPE_AGENT);
        __syncthreads();
        if (s_rank == (unsigned)(SLICES - 1)) {
            // all 32 slices of this chunk's Hs are visible -> next-layer U,V,R
            int grp = threadIdx.x >> 5, f = threadIdx.x & 31;
            int cstart = chunk * TILE;
            for (int t = 0; t < TILE / 8; ++t) {
                int nd = cstart + t * 8 + grp;
                if (nd < N_) {                    // uniform within the 32-lane group
                    float hv = Hs[(size_t)f * N_ + nd];
                    float u = 0.f, v = 0.f, r = bi2[f];
                    #pragma unroll
                    for (int k = 0; k < H; ++k) {
                        float hk = __shfl(hv, k, 32);
                        u = fmaf(hk, A2[k * H + f], u);
                        v = fmaf(hk, B2[k * H + f], v);
                        r = fmaf(hk, Rw2[k * H + f], r);
                    }
                    UVo[(size_t)f * N_ + nd] = bf16r(u) | (bf16r(v) << 16);
                    Ro [(size_t)f * N_ + nd] = r;
                }
            }
        }
    }
}

// ---------------- per-graph pooling + readout: 64 independent blocks, NO atomics ----------

__global__ __launch_bounds__(256) void k_pool(
        const float* __restrict__ Hs, const int* __restrict__ startsP,
        const float* __restrict__ w1, const float* __restrict__ b1,
        const float* __restrict__ w2, const float* __restrict__ b2,
        float* __restrict__ out) {
    __shared__ int sst[G];
    __shared__ float ga[32], gm[32], gx[32];
    int tid = threadIdx.x;
    if (tid < G) sst[tid] = startsP[tid];
    __syncthreads();
    int g = blockIdx.x;
    int sp = sst[g];
    int s = 0, e = 0;
    if (sp != 0) {
        s = sp - 1;
        e = N_;
        for (int j = g + 1; j < G; ++j)
            if (sst[j]) { e = sst[j] - 1; break; }
    }
    int f = tid >> 3, oct = tid & 7;
    float sum = 0.f, mx = 0.f;
    for (int n = s + oct; n < e; n += 8) {
        float w = Hs[(size_t)f * N_ + n];
        sum += w;
        mx = fmaxf(mx, w);
    }
    sum += __shfl_xor(sum, 1); mx = fmaxf(mx, __shfl_xor(mx, 1));
    sum += __shfl_xor(sum, 2); mx = fmaxf(mx, __shfl_xor(mx, 2));
    sum += __shfl_xor(sum, 4); mx = fmaxf(mx, __shfl_xor(mx, 4));
    if (oct == 0) {
        float c = fmaxf((float)(e - s), 1.0f);
        ga[f] = sum;
        gm[f] = sum / c;
        gx[f] = mx;
    }
    __syncthreads();
    if (tid < 32) {
        float hacc = b1[tid];
        #pragma unroll
        for (int k = 0; k < H; ++k) {
            hacc = fmaf(ga[k], w1[k * H + tid], hacc);
            hacc = fmaf(gm[k], w1[(H + k) * H + tid], hacc);
            hacc = fmaf(gx[k], w1[(2 * H + k) * H + tid], hacc);
        }
        float hid = fmaxf(hacc, 0.f);
        float p0 = hid * w2[tid * 2 + 0];
        float p1 = hid * w2[tid * 2 + 1];
        #pragma unroll
        for (int offq = 16; offq; offq >>= 1) {
            p0 += __shfl_xor(p0, offq, 32);
            p1 += __shfl_xor(p1, offq, 32);
        }
        if (tid == 0) {
            float l0 = p0 + b2[0], l1 = p1 + b2[1];
            float m = fmaxf(l0, l1);
            float lse = m + logf(expf(l0 - m) + expf(l1 - m));
            out[g * 2 + 0] = l0 - lse;
            out[g * 2 + 1] = l1 - lse;
        }
    }
}

// ---------------- launch ----------------

extern "C" void kernel_launch(void* const* d_in, const int* in_sizes, int n_in,
                              void* d_out, int out_size, void* d_ws, size_t ws_size,
                              hipStream_t stream) {
    const float* x      = (const float*)d_in[0];
    const int*   ei     = (const int*)  d_in[1];
    const float* ea     = (const float*)d_in[2];
    const int*   batch  = (const int*)  d_in[3];
    const float* nn_w1  = (const float*)d_in[4];
    const float* nn_b1  = (const float*)d_in[5];
    const float* root1  = (const float*)d_in[6];
    const float* bias1  = (const float*)d_in[7];
    const float* nn_w2  = (const float*)d_in[8];
    const float* nn_b2  = (const float*)d_in[9];
    const float* root2  = (const float*)d_in[10];
    const float* bias2  = (const float*)d_in[11];
    const float* nn_w3  = (const float*)d_in[12];
    const float* nn_b3  = (const float*)d_in[13];
    const float* root3  = (const float*)d_in[14];
    const float* bias3  = (const float*)d_in[15];
    const float* lin1_w = (const float*)d_in[16];
    const float* lin1_b = (const float*)d_in[17];
    const float* lin2_w = (const float*)d_in[18];
    const float* lin2_b = (const float*)d_in[19];
    float* out = (float*)d_out;

    char* ws = (char*)d_ws;
    size_t off = 0;
    auto alloc = [&](size_t bytes) -> void* {
        void* p = ws + off;
        off += (bytes + 255) & ~(size_t)255;
        return p;
    };
    // zero-init chunk: counts | startsP | tickets (2 x CHUNKS)
    const size_t zbytes = N_ * sizeof(int) + G * sizeof(int) + 2 * CHUNKS * sizeof(unsigned);
    char* zchunk = (char*)alloc(zbytes);
    int*  counts  = (int*)zchunk;
    int*  startsP = (int*)(zchunk + N_ * sizeof(int));
    unsigned* tick1 = (unsigned*)(startsP + G);
    unsigned* tick2 = tick1 + CHUNKS;
    unsigned* meta2 = (unsigned*)alloc((size_t)NB_ * ROW * sizeof(unsigned)); // 3.93 MB
    unsigned* UVs1 = (unsigned*)alloc((size_t)H * N_ * sizeof(unsigned));
    unsigned* UVs2 = (unsigned*)alloc((size_t)H * N_ * sizeof(unsigned));
    unsigned* UVs3 = (unsigned*)alloc((size_t)H * N_ * sizeof(unsigned));
    float* Rs1 = (float*)alloc((size_t)H * N_ * sizeof(float));
    float* Rs2 = (float*)alloc((size_t)H * N_ * sizeof(float));
    float* Rs3 = (float*)alloc((size_t)H * N_ * sizeof(float));
    float* h1  = (float*)alloc((size_t)H * N_ * sizeof(float));   // slice-major
    float* h2  = (float*)alloc((size_t)H * N_ * sizeof(float));
    float* h3  = (float*)alloc((size_t)H * N_ * sizeof(float));

    hipMemsetAsync(zchunk, 0, zbytes, stream);

    k_build_pre1<<<EBLK + PBLK, 256, 0, stream>>>(ei, ea, x, batch,
                                                  nn_w1, nn_b1, root1, bias1,
                                                  counts, meta2, UVs1, Rs1, startsP);

    // layer 1 agg + fused layer-2 precompute
    k_agg_lds<true><<<SLICES * CHUNKS, 256, 0, stream>>>(
        counts, meta2, UVs1, Rs1, h1,
        nn_w2, nn_b2, root2, bias2, UVs2, Rs2, tick1);
    // layer 2 agg + fused layer-3 precompute
    k_agg_lds<true><<<SLICES * CHUNKS, 256, 0, stream>>>(
        counts, meta2, UVs2, Rs2, h2,
        nn_w3, nn_b3, root3, bias3, UVs3, Rs3, tick2);
    // layer 3 agg (no pre)
    k_agg_lds<false><<<SLICES * CHUNKS, 256, 0, stream>>>(
        counts, meta2, UVs3, Rs3, h3,
        nullptr, nullptr, nullptr, nullptr, nullptr, nullptr, nullptr);

    k_pool<<<G, 256, 0, stream>>>(h3, startsP, lin1_w, lin1_b, lin2_w, lin2_b, out);
}

// Round 13
// 451.531 us; speedup vs baseline: 1.1207x; 1.1207x over previous
//
#include <hip/hip_runtime.h>

// Problem constants (fixed by reference)
constexpr int N_  = 10000;   // nodes (< 65536 -> u16 src)
constexpr int E_  = 320000;  // edges
constexpr int F1  = 33;      // input features
constexpr int H   = 32;      // hidden
constexpr int G   = 64;      // graphs
constexpr int CAP = 96;      // padded CSR slots/node (deg~Poisson(32), P(overflow)~1e-18/node)
constexpr int NB_ = 1280;    // node-blocks of 8
constexpr int ROW = CAP * 8; // 768 dwords per node-block row in transposed meta

constexpr int EBLK = E_ / 256;   // 1250 edge blocks
constexpr int PBLK = N_ / 8;     // 1250 node-group tasks
constexpr int SLICES = 32;
constexpr int CHUNKS = 32;       // 1024 agg blocks; 40KB LDS -> 4 blocks/CU
constexpr int TILE   = 320;
constexpr int ITERS  = TILE / 32;

// round-to-nearest-even f32 -> bf16 (low 16 bits)
__device__ __forceinline__ unsigned bf16r(float x) {
    unsigned u = __float_as_uint(x);
    return (u + 0x7FFFu + ((u >> 16) & 1u)) >> 16;
}

// transposed meta slot address: node n, slot pos
__device__ __forceinline__ size_t mslot(int n, int pos) {
    return (size_t)(n >> 3) * ROW + (size_t)(pos >> 3) * 64 + (n & 7) * 8 + (pos & 7);
}

// coherent (agent-scope, L2-bypassing) store/load for same-dispatch cross-block dataflow.
// NO __threadfence() anywhere — R12 showed device fences per-block cause wbl2 storms.
__device__ __forceinline__ void cstore(float* p, float v) {
    __hip_atomic_store(p, v, __ATOMIC_RELAXED, __HIP_MEMORY_SCOPE_AGENT);
}
__device__ __forceinline__ float cload(const float* p) {
    return __hip_atomic_load(p, __ATOMIC_RELAXED, __HIP_MEMORY_SCOPE_AGENT);
}

// ---------------- build: padded CSR (transposed) + layer-1 precompute + zero pool/ticks ----

__global__ __launch_bounds__(256) void k_build_pre1(
        const int* __restrict__ ei, const float* __restrict__ ea,
        const float* __restrict__ x,
        const float* __restrict__ A, const float* __restrict__ Bm,
        const float* __restrict__ Rw, const float* __restrict__ bias,
        unsigned* __restrict__ counts, unsigned* __restrict__ meta2,
        unsigned* __restrict__ UVs, float* __restrict__ Rs,
        unsigned* __restrict__ zbase, int zn) {
    __shared__ unsigned s_uv[32][9];
    __shared__ float    s_r[32][9];
    if (blockIdx.x < EBLK) {
        int e = blockIdx.x * 256 + threadIdx.x;
        int s = ei[e];
        int d = ei[E_ + e];
        int pos = (int)atomicAdd(&counts[d], 1u);
        meta2[mslot(d, pos)] = (unsigned)s | (bf16r(ea[e]) << 16);
    } else {
        if (blockIdx.x == EBLK) {   // zero pool buffers + tickets (visible next dispatch)
            for (int i = threadIdx.x; i < zn; i += 256) zbase[i] = 0u;
        }
        int base8 = (blockIdx.x - EBLK) * 8;
        int grp = threadIdx.x >> 5;
        int f = threadIdx.x & 31;
        int node = base8 + grp;
        float u = 0.f, v = 0.f, r = bias[f];
        const float* xr = x + (size_t)node * F1;
        #pragma unroll
        for (int k = 0; k < F1; ++k) {
            float xv = xr[k];
            u = fmaf(xv, A[k * H + f], u);
            v = fmaf(xv, Bm[k * H + f], v);
            r = fmaf(xv, Rw[k * H + f], r);
        }
        s_uv[f][grp] = bf16r(u) | (bf16r(v) << 16);
        s_r[f][grp]  = r;
        __syncthreads();
        int fo = threadIdx.x >> 3;
        int nl = threadIdx.x & 7;
        UVs[(size_t)fo * N_ + base8 + nl] = s_uv[fo][nl];
        Rs [(size_t)fo * N_ + base8 + nl] = s_r [fo][nl];
    }
}

// ---------------- fused agg (+ per-chunk pre OR pooling+readout) ----------------
// MODE 1: after agg, last slice-block of each chunk (acq_rel ticket) computes next-layer
//         U,V,R for its 320 nodes. MODE 2: per-block pooled partial atomics + global
//         ticket readout. Cross-block Hs flows through coherent stores/loads only.

template<int MODE>
__global__ __launch_bounds__(256) void k_agg(
        const unsigned* __restrict__ counts, const unsigned* __restrict__ meta2,
        const unsigned* __restrict__ UVs, const float* __restrict__ Rs,
        float* __restrict__ Hs,
        const float* __restrict__ A2, const float* __restrict__ B2,
        const float* __restrict__ Rw2, const float* __restrict__ bi2,
        unsigned* __restrict__ UVo, float* __restrict__ Ro,
        unsigned* __restrict__ tick,
        const int* __restrict__ batch, float* __restrict__ add_p,
        unsigned* __restrict__ max_p, float* __restrict__ cnt_p,
        const float* __restrict__ w1, const float* __restrict__ b1,
        const float* __restrict__ w2, const float* __restrict__ b2,
        float* __restrict__ out) {
    __shared__ __align__(16) unsigned uvl[N_];
    __shared__ unsigned s_rank;
    int s     = blockIdx.x & 31;
    int chunk = blockIdx.x >> 5;

    int l   = threadIdx.x & 63;
    int wav = threadIdx.x >> 6;
    int j0  = l & 7;
    int nl  = l >> 3;

    // ---- initial prefetch (overlaps LDS fill) ----
    int cbase = chunk * TILE + wav * 8;
    int node = cbase + nl;
    int nc = min(node, N_ - 1);
    int dg = (node < N_) ? (int)counts[nc] : 0;
    float rv = Rs[(size_t)s * N_ + nc];
    const unsigned* mrow = meta2 + (size_t)(cbase >> 3) * ROW + l;
    unsigned m0 = mrow[0], m1 = mrow[64], m2 = mrow[128],
             m3 = mrow[192], m4 = mrow[256], m5 = mrow[320];

    // ---- fill LDS with this slice's UV table ----
    const unsigned* srcp = UVs + (size_t)s * N_;
    #pragma unroll
    for (int i = 0; i < 10; ++i) {
        int d4 = (i * 256 + threadIdx.x) * 4;
        if (d4 + 4 <= N_) {
            uint4 t = *reinterpret_cast<const uint4*>(srcp + d4);
            *reinterpret_cast<uint4*>(&uvl[d4]) = t;
        }
    }
    __syncthreads();

    for (int it = 0; it < ITERS; ++it) {
        int nbase = cbase + 32;
        int nnode = nbase + nl;
        int nnc = min(nnode, N_ - 1);
        int ndg = 0; float nrv = 0.f;
        unsigned n0 = 0, n1 = 0, n2 = 0, n3 = 0, n4 = 0, n5 = 0;
        if (it < ITERS - 1) {
            ndg = (nnode < N_) ? (int)counts[nnc] : 0;
            nrv = Rs[(size_t)s * N_ + nnc];
            const unsigned* nmr = meta2 + (size_t)(nbase >> 3) * ROW + l;
            n0 = nmr[0]; n1 = nmr[64]; n2 = nmr[128];
            n3 = nmr[192]; n4 = nmr[256]; n5 = nmr[320];
        }

        int maxd = dg;
        maxd = max(maxd, __shfl_xor(maxd, 8));
        maxd = max(maxd, __shfl_xor(maxd, 16));
        maxd = max(maxd, __shfl_xor(maxd, 32));
        float acc = 0.f;
        auto slot = [&](int p, unsigned mv) {
            unsigned idx = min(mv & 0xFFFFu, (unsigned)(N_ - 1));
            unsigned w = uvl[idx];
            float t = fmaf(__uint_as_float(mv & 0xFFFF0000u),
                           __uint_as_float(w << 16),
                           __uint_as_float(w & 0xFFFF0000u));
            if (j0 + 8 * p < dg) acc += t;
        };
        if (maxd > 0)  slot(0, m0);
        if (maxd > 8)  slot(1, m1);
        if (maxd > 16) slot(2, m2);
        if (maxd > 24) slot(3, m3);
        if (maxd > 32) slot(4, m4);
        if (maxd > 40) slot(5, m5);
        if (maxd > 48) {
            const unsigned* trow = meta2 + (size_t)(cbase >> 3) * ROW + l;
            for (int p = 6; 8 * p < maxd; ++p)
                slot(p, trow[p * 64]);
        }
        acc += __shfl_xor(acc, 1);
        acc += __shfl_xor(acc, 2);
        acc += __shfl_xor(acc, 4);
        float h = fmaxf(rv + acc, 0.f);
        if (j0 == 0 && node < N_) cstore(&Hs[(size_t)s * N_ + node], h);

        cbase = nbase; node = nnode; nc = nnc; dg = ndg; rv = nrv;
        m0 = n0; m1 = n1; m2 = n2; m3 = n3; m4 = n4; m5 = n5;
    }

    if constexpr (MODE == 1) {
        // per-chunk ticket: last of the 32 slice-blocks computes next-layer U,V,R
        __syncthreads();   // barrier drains vmcnt -> all coherent Hs stores complete
        if (threadIdx.x == 0)
            s_rank = __hip_atomic_fetch_add(&tick[chunk], 1u, __ATOMIC_ACQ_REL,
                                            __HIP_MEMORY_SCOPE_AGENT);
        __syncthreads();
        if (s_rank == (unsigned)(SLICES - 1)) {
            auto s_uv = (unsigned(*)[9])uvl;                     // reuse LDS
            auto s_r  = (float(*)[9])(uvl + 32 * 9 + 8);
            int grp = threadIdx.x >> 5, f = threadIdx.x & 31;
            int fo = threadIdx.x >> 3, pnl = threadIdx.x & 7;
            int cstart = chunk * TILE;
            for (int t = 0; t < TILE / 8; ++t) {
                int base8 = cstart + t * 8;
                int nd = base8 + grp;
                float u = 0.f, v = 0.f, r = bi2[f];
                if (nd < N_) {
                    float hv = cload(&Hs[(size_t)f * N_ + nd]);
                    #pragma unroll
                    for (int k = 0; k < H; ++k) {
                        float hk = __shfl(hv, k, 32);
                        u = fmaf(hk, A2[k * H + f], u);
                        v = fmaf(hk, B2[k * H + f], v);
                        r = fmaf(hk, Rw2[k * H + f], r);
                    }
                }
                s_uv[f][grp] = bf16r(u) | (bf16r(v) << 16);
                s_r[f][grp]  = r;
                __syncthreads();
                int nd2 = base8 + pnl;
                if (nd2 < N_) {
                    UVo[(size_t)fo * N_ + nd2] = s_uv[fo][pnl];
                    Ro [(size_t)fo * N_ + nd2] = s_r [fo][pnl];
                }
                __syncthreads();
            }
        }
    }

    if constexpr (MODE == 2) {
        // per-block pooled partials (LDS reduce -> few atomics), then global ticket readout
        __syncthreads();
        float*    pg  = (float*)uvl;            // reuse LDS: [G] sums
        unsigned* pmx = uvl + G;                // [G] max bits
        float*    pc  = (float*)(uvl + 2 * G);  // [G] counts
        int*      sb  = (int*)(uvl + 3 * G);    // [2] first/last graph
        int tid = threadIdx.x;
        if (tid < G) { pg[tid] = 0.f; pmx[tid] = 0u; pc[tid] = 0.f; }
        int cstart = chunk * TILE;
        int cend = min(cstart + TILE, N_);
        if (tid == 0) { sb[0] = batch[cstart]; sb[1] = batch[cend - 1]; }
        __syncthreads();
        if (tid < 64) {
            for (int q = 0; q < 5; ++q) {
                int n = cstart + tid * 5 + q;
                if (n < N_) {
                    float h = cload(&Hs[(size_t)s * N_ + n]);
                    int g = batch[n];
                    atomicAdd(&pg[g], h);
                    atomicMax(&pmx[g], __float_as_uint(h));
                    if (s == 0) atomicAdd(&pc[g], 1.0f);
                }
            }
        }
        __syncthreads();
        if (tid >= sb[0] && tid <= sb[1]) {      // tid == graph id
            atomicAdd(&add_p[tid * H + s], pg[tid]);
            atomicMax(&max_p[tid * H + s], pmx[tid]);
            if (s == 0) atomicAdd(&cnt_p[tid], pc[tid]);
        }
        __syncthreads();
        if (tid == 0)
            s_rank = __hip_atomic_fetch_add(tick, 1u, __ATOMIC_ACQ_REL,
                                            __HIP_MEMORY_SCOPE_AGENT);
        __syncthreads();
        if (s_rank == (unsigned)(SLICES * CHUNKS - 1)) {
            int grp = tid >> 5, f = tid & 31;
            for (int g = grp; g < G; g += 8) {
                float a  = add_p[g * H + f];
                float c  = fmaxf(cnt_p[g], 1.0f);
                float me = a / c;
                float mx = __uint_as_float(max_p[g * H + f]);
                float hacc = b1[f];
                #pragma unroll
                for (int k = 0; k < H; ++k) {
                    hacc = fmaf(__shfl(a,  k, 32), w1[k * H + f], hacc);
                    hacc = fmaf(__shfl(me, k, 32), w1[(H + k) * H + f], hacc);
                    hacc = fmaf(__shfl(mx, k, 32), w1[(2 * H + k) * H + f], hacc);
                }
                float hid = fmaxf(hacc, 0.f);
                float p0 = hid * w2[f * 2 + 0];
                float p1 = hid * w2[f * 2 + 1];
                #pragma unroll
                for (int offq = 16; offq; offq >>= 1) {
                    p0 += __shfl_xor(p0, offq, 32);
                    p1 += __shfl_xor(p1, offq, 32);
                }
                if (f == 0) {
                    float l0 = p0 + b2[0], l1 = p1 + b2[1];
                    float m = fmaxf(l0, l1);
                    float lse = m + logf(expf(l0 - m) + expf(l1 - m));
                    out[g * 2 + 0] = l0 - lse;
                    out[g * 2 + 1] = l1 - lse;
                }
            }
        }
    }
}

// ---------------- launch ----------------

extern "C" void kernel_launch(void* const* d_in, const int* in_sizes, int n_in,
                              void* d_out, int out_size, void* d_ws, size_t ws_size,
                              hipStream_t stream) {
    const float* x      = (const float*)d_in[0];
    const int*   ei     = (const int*)  d_in[1];
    const float* ea     = (const float*)d_in[2];
    const int*   batch  = (const int*)  d_in[3];
    const float* nn_w1  = (const float*)d_in[4];
    const float* nn_b1  = (const float*)d_in[5];
    const float* root1  = (const float*)d_in[6];
    const float* bias1  = (const float*)d_in[7];
    const float* nn_w2  = (const float*)d_in[8];
    const float* nn_b2  = (const float*)d_in[9];
    const float* root2  = (const float*)d_in[10];
    const float* bias2  = (const float*)d_in[11];
    const float* nn_w3  = (const float*)d_in[12];
    const float* nn_b3  = (const float*)d_in[13];
    const float* root3  = (const float*)d_in[14];
    const float* bias3  = (const float*)d_in[15];
    const float* lin1_w = (const float*)d_in[16];
    const float* lin1_b = (const float*)d_in[17];
    const float* lin2_w = (const float*)d_in[18];
    const float* lin2_b = (const float*)d_in[19];
    float* out = (float*)d_out;

    char* ws = (char*)d_ws;
    size_t off = 0;
    auto alloc = [&](size_t bytes) -> void* {
        void* p = ws + off;
        off += (bytes + 255) & ~(size_t)255;
        return p;
    };
    unsigned* counts = (unsigned*)alloc(N_ * sizeof(unsigned));   // memset to 0
    // pool+tickets region, zeroed inside build: add_p | max_p | cnt_p | tick1 | tick2 | tick3
    const int ZN = G * H + G * H + G + CHUNKS + CHUNKS + 1;
    unsigned* zbase = (unsigned*)alloc(ZN * sizeof(unsigned));
    float*    add_p = (float*)zbase;
    unsigned* max_p = zbase + G * H;
    float*    cnt_p = (float*)(zbase + 2 * G * H);
    unsigned* tick1 = zbase + 2 * G * H + G;
    unsigned* tick2 = tick1 + CHUNKS;
    unsigned* tick3 = tick2 + CHUNKS;
    unsigned* meta2 = (unsigned*)alloc((size_t)NB_ * ROW * sizeof(unsigned)); // 3.93 MB
    unsigned* UVs1 = (unsigned*)alloc((size_t)H * N_ * sizeof(unsigned));
    unsigned* UVs2 = (unsigned*)alloc((size_t)H * N_ * sizeof(unsigned));
    unsigned* UVs3 = (unsigned*)alloc((size_t)H * N_ * sizeof(unsigned));
    float* Rs1 = (float*)alloc((size_t)H * N_ * sizeof(float));
    float* Rs2 = (float*)alloc((size_t)H * N_ * sizeof(float));
    float* Rs3 = (float*)alloc((size_t)H * N_ * sizeof(float));
    float* h1  = (float*)alloc((size_t)H * N_ * sizeof(float));   // slice-major
    float* h2  = (float*)alloc((size_t)H * N_ * sizeof(float));
    float* h3  = (float*)alloc((size_t)H * N_ * sizeof(float));

    hipMemsetAsync(counts, 0, N_ * sizeof(unsigned), stream);

    k_build_pre1<<<EBLK + PBLK, 256, 0, stream>>>(ei, ea, x,
                                                  nn_w1, nn_b1, root1, bias1,
                                                  counts, meta2, UVs1, Rs1,
                                                  zbase, ZN);

    // layer 1 agg + fused layer-2 precompute (per-chunk ticket, coherent Hs)
    k_agg<1><<<SLICES * CHUNKS, 256, 0, stream>>>(
        counts, meta2, UVs1, Rs1, h1,
        nn_w2, nn_b2, root2, bias2, UVs2, Rs2, tick1,
        nullptr, nullptr, nullptr, nullptr,
        nullptr, nullptr, nullptr, nullptr, nullptr);
    // layer 2 agg + fused layer-3 precompute
    k_agg<1><<<SLICES * CHUNKS, 256, 0, stream>>>(
        counts, meta2, UVs2, Rs2, h2,
        nn_w3, nn_b3, root3, bias3, UVs3, Rs3, tick2,
        nullptr, nullptr, nullptr, nullptr,
        nullptr, nullptr, nullptr, nullptr, nullptr);
    // layer 3 agg + fused pooling + global-ticket readout
    k_agg<2><<<SLICES * CHUNKS, 256, 0, stream>>>(
        counts, meta2, UVs3, Rs3, h3,
        nullptr, nullptr, nullptr, nullptr, nullptr, nullptr, tick3,
        batch, add_p, max_p, cnt_p,
        lin1_w, lin1_b, lin2_w, lin2_b, out);
}

// Round 14
// 173.440 us; speedup vs baseline: 2.9177x; 2.6034x over previous
//
#include <hip/hip_runtime.h>

// Problem constants (fixed by reference)
constexpr int N_  = 10000;   // nodes (< 65536 -> u16 src)
constexpr int E_  = 320000;  // edges
constexpr int F1  = 33;      // input features
constexpr int H   = 32;      // hidden
constexpr int G   = 64;      // graphs
constexpr int CAP = 96;      // padded CSR slots/node (deg~Poisson(32), P(overflow)~1e-18/node)
constexpr int NB_ = 1280;    // node-blocks of 8 (covers 10240 >= N_)
constexpr int ROW = CAP * 8; // 768 dwords per node-block row in transposed meta

constexpr int EBLK = E_ / 256;   // 1250 edge blocks
constexpr int PBLK = N_ / 8;     // 1250 node-group tasks (8 nodes x 32 lanes)
constexpr int SLICES = 32;
constexpr int CHUNKS = 32;       // 1024 agg blocks; 40KB LDS -> 4 blocks/CU
constexpr int TILE   = 320;      // 32*320 = 10240 >= N_
// agg blocks are 512 threads = 8 waves x 8 nodes/iter -> 64 nodes/iter, 5 iters.
// 4 blocks/CU x 8 waves = 32 waves/CU = 100% wave occupancy (R11 had 16).
constexpr int AT    = 512;
constexpr int ITERS = TILE / 64;

// round-to-nearest-even f32 -> bf16 (low 16 bits)
__device__ __forceinline__ unsigned bf16r(float x) {
    unsigned u = __float_as_uint(x);
    return (u + 0x7FFFu + ((u >> 16) & 1u)) >> 16;
}

// transposed meta slot address: node n, slot pos
__device__ __forceinline__ size_t mslot(int n, int pos) {
    return (size_t)(n >> 3) * ROW + (size_t)(pos >> 3) * 64 + (n & 7) * 8 + (pos & 7);
}

// ---------------- build: padded CSR (transposed) + layer-1 precompute ----------------

__global__ __launch_bounds__(256) void k_build_pre1(
        const int* __restrict__ ei, const float* __restrict__ ea,
        const float* __restrict__ x, const int* __restrict__ batch,
        const float* __restrict__ A, const float* __restrict__ Bm,
        const float* __restrict__ Rw, const float* __restrict__ bias,
        int* __restrict__ counts, unsigned* __restrict__ meta2,
        unsigned* __restrict__ UVs, float* __restrict__ Rs,
        int* __restrict__ startsP) {
    __shared__ unsigned s_uv[32][9];
    __shared__ float    s_r[32][9];
    if (blockIdx.x < EBLK) {
        int e = blockIdx.x * 256 + threadIdx.x;
        int s = ei[e];
        int d = ei[E_ + e];
        int pos = atomicAdd(&counts[d], 1);
        meta2[mslot(d, pos)] = (unsigned)s | (bf16r(ea[e]) << 16);
    } else {
        int base8 = (blockIdx.x - EBLK) * 8;
        int grp = threadIdx.x >> 5;
        int f = threadIdx.x & 31;
        int node = base8 + grp;
        if (f == 0) {   // graph-boundary detection (batch sorted)
            int b = batch[node];
            int bp = (node == 0) ? -1 : batch[node - 1];
            if (b != bp) startsP[b] = node + 1;
        }
        float u = 0.f, v = 0.f, r = bias[f];
        const float* xr = x + (size_t)node * F1;
        #pragma unroll
        for (int k = 0; k < F1; ++k) {
            float xv = xr[k];
            u = fmaf(xv, A[k * H + f], u);
            v = fmaf(xv, Bm[k * H + f], v);
            r = fmaf(xv, Rw[k * H + f], r);
        }
        s_uv[f][grp] = bf16r(u) | (bf16r(v) << 16);
        s_r[f][grp]  = r;
        __syncthreads();
        int fo = threadIdx.x >> 3;
        int nl = threadIdx.x & 7;
        UVs[(size_t)fo * N_ + base8 + nl] = s_uv[fo][nl];
        Rs [(size_t)fo * N_ + base8 + nl] = s_r [fo][nl];
    }
}

// ---------------- per-layer precompute from slice-major h ----------------

__global__ __launch_bounds__(256) void k_pre(
        const float* __restrict__ Hs,
        const float* __restrict__ A, const float* __restrict__ Bm,
        const float* __restrict__ Rw, const float* __restrict__ bias,
        unsigned* __restrict__ UVs, float* __restrict__ Rs) {
    __shared__ unsigned s_uv[32][9];
    __shared__ float    s_r[32][9];
    int base8 = blockIdx.x * 8;
    int grp = threadIdx.x >> 5;
    int f = threadIdx.x & 31;
    int node = base8 + grp;
    float hv = Hs[(size_t)f * N_ + node];
    float u = 0.f, v = 0.f, r = bias[f];
    #pragma unroll
    for (int k = 0; k < H; ++k) {
        float hk = __shfl(hv, k, 32);
        u = fmaf(hk, A[k * H + f], u);
        v = fmaf(hk, Bm[k * H + f], v);
        r = fmaf(hk, Rw[k * H + f], r);
    }
    s_uv[f][grp] = bf16r(u) | (bf16r(v) << 16);
    s_r[f][grp]  = r;
    __syncthreads();
    int fo = threadIdx.x >> 3;
    int nl = threadIdx.x & 7;
    UVs[(size_t)fo * N_ + base8 + nl] = s_uv[fo][nl];
    Rs [(size_t)fo * N_ + base8 + nl] = s_r [fo][nl];
}

// ---------------- LDS-sliced conv aggregation, 512-thread blocks (32 waves/CU) ----------
// block = (slice s, 320-node chunk). LDS = full per-feature UV table (40 KB).
// 8 waves x (8 nodes x 8 slots); meta rotate-prefetched; h written slice-major.

__global__ __launch_bounds__(512, 8) void k_agg_lds(
        const int* __restrict__ counts, const unsigned* __restrict__ meta2,
        const unsigned* __restrict__ UVs, const float* __restrict__ Rs,
        float* __restrict__ Hs) {
    __shared__ __align__(16) unsigned uvl[N_];
    int s     = blockIdx.x & 31;
    int chunk = blockIdx.x >> 5;

    int l   = threadIdx.x & 63;
    int wav = threadIdx.x >> 6;      // 0..7
    int j0  = l & 7;                 // slot within group
    int nl  = l >> 3;                // node within wave (0..7)

    // ---- initial prefetch (overlaps LDS fill) ----
    int cbase = chunk * TILE + wav * 8;
    int node = cbase + nl;
    int nc = min(node, N_ - 1);
    int dg = (node < N_) ? counts[nc] : 0;
    float rv = Rs[(size_t)s * N_ + nc];
    const unsigned* mrow = meta2 + (size_t)(cbase >> 3) * ROW + l;
    unsigned m0 = mrow[0], m1 = mrow[64], m2 = mrow[128],
             m3 = mrow[192], m4 = mrow[256], m5 = mrow[320];

    // ---- fill LDS with this slice's UV table (coalesced 40 KB) ----
    const unsigned* srcp = UVs + (size_t)s * N_;
    #pragma unroll
    for (int i = 0; i < 5; ++i) {
        int d4 = (i * AT + threadIdx.x) * 4;
        if (d4 + 4 <= N_) {
            uint4 t = *reinterpret_cast<const uint4*>(srcp + d4);
            *reinterpret_cast<uint4*>(&uvl[d4]) = t;
        }
    }
    __syncthreads();

    for (int it = 0; it < ITERS; ++it) {
        // ---- prefetch next group (64 nodes ahead) ----
        int nbase = cbase + 64;
        int nnode = nbase + nl;
        int nnc = min(nnode, N_ - 1);
        int ndg = 0; float nrv = 0.f;
        unsigned n0 = 0, n1 = 0, n2 = 0, n3 = 0, n4 = 0, n5 = 0;
        if (it < ITERS - 1) {
            ndg = (nnode < N_) ? counts[nnc] : 0;
            nrv = Rs[(size_t)s * N_ + nnc];
            const unsigned* nmr = meta2 + (size_t)(nbase >> 3) * ROW + l;
            n0 = nmr[0]; n1 = nmr[64]; n2 = nmr[128];
            n3 = nmr[192]; n4 = nmr[256]; n5 = nmr[320];
        }

        // ---- compute current group ----
        int maxd = dg;
        maxd = max(maxd, __shfl_xor(maxd, 8));
        maxd = max(maxd, __shfl_xor(maxd, 16));
        maxd = max(maxd, __shfl_xor(maxd, 32));
        float acc = 0.f;
        auto slot = [&](int p, unsigned mv) {
            unsigned idx = min(mv & 0xFFFFu, (unsigned)(N_ - 1));
            unsigned w = uvl[idx];
            float t = fmaf(__uint_as_float(mv & 0xFFFF0000u),   // a (bf16 hi)
                           __uint_as_float(w << 16),            // u
                           __uint_as_float(w & 0xFFFF0000u));   // v
            if (j0 + 8 * p < dg) acc += t;
        };
        if (maxd > 0)  slot(0, m0);
        if (maxd > 8)  slot(1, m1);
        if (maxd > 16) slot(2, m2);
        if (maxd > 24) slot(3, m3);
        if (maxd > 32) slot(4, m4);
        if (maxd > 40) slot(5, m5);
        if (maxd > 48) {                       // rare tail
            const unsigned* trow = meta2 + (size_t)(cbase >> 3) * ROW + l;
            for (int p = 6; 8 * p < maxd; ++p)
                slot(p, trow[p * 64]);
        }
        acc += __shfl_xor(acc, 1);
        acc += __shfl_xor(acc, 2);
        acc += __shfl_xor(acc, 4);
        float h = fmaxf(rv + acc, 0.f);
        if (j0 == 0 && node < N_) Hs[(size_t)s * N_ + node] = h;

        cbase = nbase; node = nnode; nc = nnc; dg = ndg; rv = nrv;
        m0 = n0; m1 = n1; m2 = n2; m3 = n3; m4 = n4; m5 = n5;
    }
}

// ---------------- per-graph pooling + readout: 64 independent blocks, NO atomics ----------

__global__ __launch_bounds__(256) void k_pool(
        const float* __restrict__ Hs, const int* __restrict__ startsP,
        const float* __restrict__ w1, const float* __restrict__ b1,
        const float* __restrict__ w2, const float* __restrict__ b2,
        float* __restrict__ out) {
    __shared__ int sst[G];
    __shared__ float ga[32], gm[32], gx[32];
    int tid = threadIdx.x;
    if (tid < G) sst[tid] = startsP[tid];
    __syncthreads();
    int g = blockIdx.x;
    int sp = sst[g];
    int s = 0, e = 0;
    if (sp != 0) {
        s = sp - 1;
        e = N_;
        for (int j = g + 1; j < G; ++j)
            if (sst[j]) { e = sst[j] - 1; break; }
    }
    int f = tid >> 3, oct = tid & 7;
    float sum = 0.f, mx = 0.f;
    for (int n = s + oct; n < e; n += 8) {
        float w = Hs[(size_t)f * N_ + n];
        sum += w;
        mx = fmaxf(mx, w);
    }
    sum += __shfl_xor(sum, 1); mx = fmaxf(mx, __shfl_xor(mx, 1));
    sum += __shfl_xor(sum, 2); mx = fmaxf(mx, __shfl_xor(mx, 2));
    sum += __shfl_xor(sum, 4); mx = fmaxf(mx, __shfl_xor(mx, 4));
    if (oct == 0) {
        float c = fmaxf((float)(e - s), 1.0f);
        ga[f] = sum;
        gm[f] = sum / c;
        gx[f] = mx;
    }
    __syncthreads();
    if (tid < 32) {
        float hacc = b1[tid];
        #pragma unroll
        for (int k = 0; k < H; ++k) {
            hacc = fmaf(ga[k], w1[k * H + tid], hacc);
            hacc = fmaf(gm[k], w1[(H + k) * H + tid], hacc);
            hacc = fmaf(gx[k], w1[(2 * H + k) * H + tid], hacc);
        }
        float hid = fmaxf(hacc, 0.f);
        float p0 = hid * w2[tid * 2 + 0];
        float p1 = hid * w2[tid * 2 + 1];
        #pragma unroll
        for (int offq = 16; offq; offq >>= 1) {
            p0 += __shfl_xor(p0, offq, 32);
            p1 += __shfl_xor(p1, offq, 32);
        }
        if (tid == 0) {
            float l0 = p0 + b2[0], l1 = p1 + b2[1];
            float m = fmaxf(l0, l1);
            float lse = m + logf(expf(l0 - m) + expf(l1 - m));
            out[g * 2 + 0] = l0 - lse;
            out[g * 2 + 1] = l1 - lse;
        }
    }
}

// ---------------- launch ----------------

extern "C" void kernel_launch(void* const* d_in, const int* in_sizes, int n_in,
                              void* d_out, int out_size, void* d_ws, size_t ws_size,
                              hipStream_t stream) {
    const float* x      = (const float*)d_in[0];
    const int*   ei     = (const int*)  d_in[1];
    const float* ea     = (const float*)d_in[2];
    const int*   batch  = (const int*)  d_in[3];
    const float* nn_w1  = (const float*)d_in[4];
    const float* nn_b1  = (const float*)d_in[5];
    const float* root1  = (const float*)d_in[6];
    const float* bias1  = (const float*)d_in[7];
    const float* nn_w2  = (const float*)d_in[8];
    const float* nn_b2  = (const float*)d_in[9];
    const float* root2  = (const float*)d_in[10];
    const float* bias2  = (const float*)d_in[11];
    const float* nn_w3  = (const float*)d_in[12];
    const float* nn_b3  = (const float*)d_in[13];
    const float* root3  = (const float*)d_in[14];
    const float* bias3  = (const float*)d_in[15];
    const float* lin1_w = (const float*)d_in[16];
    const float* lin1_b = (const float*)d_in[17];
    const float* lin2_w = (const float*)d_in[18];
    const float* lin2_b = (const float*)d_in[19];
    float* out = (float*)d_out;

    char* ws = (char*)d_ws;
    size_t off = 0;
    auto alloc = [&](size_t bytes) -> void* {
        void* p = ws + off;
        off += (bytes + 255) & ~(size_t)255;
        return p;
    };
    // zero-init chunk: counts | startsP
    const size_t zbytes = N_ * sizeof(int) + G * sizeof(int);
    char* zchunk = (char*)alloc(zbytes);
    int*  counts  = (int*)zchunk;
    int*  startsP = (int*)(zchunk + N_ * sizeof(int));
    unsigned* meta2 = (unsigned*)alloc((size_t)NB_ * ROW * sizeof(unsigned)); // 3.93 MB
    unsigned* UVs1 = (unsigned*)alloc((size_t)H * N_ * sizeof(unsigned));
    unsigned* UVs2 = (unsigned*)alloc((size_t)H * N_ * sizeof(unsigned));
    unsigned* UVs3 = (unsigned*)alloc((size_t)H * N_ * sizeof(unsigned));
    float* Rs1 = (float*)alloc((size_t)H * N_ * sizeof(float));
    float* Rs2 = (float*)alloc((size_t)H * N_ * sizeof(float));
    float* Rs3 = (float*)alloc((size_t)H * N_ * sizeof(float));
    float* h1  = (float*)alloc((size_t)H * N_ * sizeof(float));   // slice-major
    float* h2  = (float*)alloc((size_t)H * N_ * sizeof(float));
    float* h3  = (float*)alloc((size_t)H * N_ * sizeof(float));

    hipMemsetAsync(zchunk, 0, zbytes, stream);

    k_build_pre1<<<EBLK + PBLK, 256, 0, stream>>>(ei, ea, x, batch,
                                                  nn_w1, nn_b1, root1, bias1,
                                                  counts, meta2, UVs1, Rs1, startsP);

    k_agg_lds<<<SLICES * CHUNKS, AT, 0, stream>>>(counts, meta2, UVs1, Rs1, h1);
    k_pre    <<<PBLK, 256, 0, stream>>>(h1, nn_w2, nn_b2, root2, bias2, UVs2, Rs2);
    k_agg_lds<<<SLICES * CHUNKS, AT, 0, stream>>>(counts, meta2, UVs2, Rs2, h2);
    k_pre    <<<PBLK, 256, 0, stream>>>(h2, nn_w3, nn_b3, root3, bias3, UVs3, Rs3);
    k_agg_lds<<<SLICES * CHUNKS, AT, 0, stream>>>(counts, meta2, UVs3, Rs3, h3);

    k_pool<<<G, 256, 0, stream>>>(h3, startsP, lin1_w, lin1_b, lin2_w, lin2_b, out);
}

// Round 15
// 167.801 us; speedup vs baseline: 3.0158x; 1.0336x over previous
//
#include <hip/hip_runtime.h>

// Problem constants (fixed by reference)
constexpr int N_  = 10000;   // nodes (< 65536 -> u16 src)
constexpr int E_  = 320000;  // edges
constexpr int F1  = 33;      // input features
constexpr int H   = 32;      // hidden
constexpr int G   = 64;      // graphs
constexpr int CAP = 96;      // padded CSR slots/node (deg~Poisson(32), P(overflow)~1e-18/node)
constexpr int NB_ = 1280;    // node-blocks of 8 (covers 10240 >= N_)
constexpr int ROW = CAP * 8; // 768 dwords per node-block row in transposed meta

constexpr int EBLK = E_ / 256;   // 1250 edge blocks
constexpr int PBLK = N_ / 8;     // 1250 node-group tasks (8 nodes x 32 lanes)
constexpr int SLICES = 32;
constexpr int CHUNKS = 16;       // 512 agg blocks
constexpr int TILE   = 640;      // 16*640 = 10240 >= N_
// agg blocks: 1024 threads = 16 waves x 8 nodes -> 128 nodes/iter, 5 iters.
// 2 blocks/CU (thread-capped) x 16 waves = 32 waves/CU, and the redundant
// 40KB UV fill happens 512x instead of 1024x (20MB vs 40MB per dispatch).
constexpr int AT    = 1024;
constexpr int ITERS = TILE / 128;

// round-to-nearest-even f32 -> bf16 (low 16 bits)
__device__ __forceinline__ unsigned bf16r(float x) {
    unsigned u = __float_as_uint(x);
    return (u + 0x7FFFu + ((u >> 16) & 1u)) >> 16;
}

// transposed meta slot address: node n, slot pos
__device__ __forceinline__ size_t mslot(int n, int pos) {
    return (size_t)(n >> 3) * ROW + (size_t)(pos >> 3) * 64 + (n & 7) * 8 + (pos & 7);
}

// ---------------- build: padded CSR (transposed) + layer-1 precompute ----------------

__global__ __launch_bounds__(256) void k_build_pre1(
        const int* __restrict__ ei, const float* __restrict__ ea,
        const float* __restrict__ x, const int* __restrict__ batch,
        const float* __restrict__ A, const float* __restrict__ Bm,
        const float* __restrict__ Rw, const float* __restrict__ bias,
        int* __restrict__ counts, unsigned* __restrict__ meta2,
        unsigned* __restrict__ UVs, float* __restrict__ Rs,
        int* __restrict__ startsP) {
    __shared__ unsigned s_uv[32][9];
    __shared__ float    s_r[32][9];
    if (blockIdx.x < EBLK) {
        int e = blockIdx.x * 256 + threadIdx.x;
        int s = ei[e];
        int d = ei[E_ + e];
        int pos = atomicAdd(&counts[d], 1);
        meta2[mslot(d, pos)] = (unsigned)s | (bf16r(ea[e]) << 16);
    } else {
        int base8 = (blockIdx.x - EBLK) * 8;
        int grp = threadIdx.x >> 5;
        int f = threadIdx.x & 31;
        int node = base8 + grp;
        if (f == 0) {   // graph-boundary detection (batch sorted)
            int b = batch[node];
            int bp = (node == 0) ? -1 : batch[node - 1];
            if (b != bp) startsP[b] = node + 1;
        }
        float u = 0.f, v = 0.f, r = bias[f];
        const float* xr = x + (size_t)node * F1;
        #pragma unroll
        for (int k = 0; k < F1; ++k) {
            float xv = xr[k];
            u = fmaf(xv, A[k * H + f], u);
            v = fmaf(xv, Bm[k * H + f], v);
            r = fmaf(xv, Rw[k * H + f], r);
        }
        s_uv[f][grp] = bf16r(u) | (bf16r(v) << 16);
        s_r[f][grp]  = r;
        __syncthreads();
        int fo = threadIdx.x >> 3;
        int nl = threadIdx.x & 7;
        UVs[(size_t)fo * N_ + base8 + nl] = s_uv[fo][nl];
        Rs [(size_t)fo * N_ + base8 + nl] = s_r [fo][nl];
    }
}

// ---------------- per-layer precompute from slice-major h ----------------

__global__ __launch_bounds__(256) void k_pre(
        const float* __restrict__ Hs,
        const float* __restrict__ A, const float* __restrict__ Bm,
        const float* __restrict__ Rw, const float* __restrict__ bias,
        unsigned* __restrict__ UVs, float* __restrict__ Rs) {
    __shared__ unsigned s_uv[32][9];
    __shared__ float    s_r[32][9];
    int base8 = blockIdx.x * 8;
    int grp = threadIdx.x >> 5;
    int f = threadIdx.x & 31;
    int node = base8 + grp;
    float hv = Hs[(size_t)f * N_ + node];
    float u = 0.f, v = 0.f, r = bias[f];
    #pragma unroll
    for (int k = 0; k < H; ++k) {
        float hk = __shfl(hv, k, 32);
        u = fmaf(hk, A[k * H + f], u);
        v = fmaf(hk, Bm[k * H + f], v);
        r = fmaf(hk, Rw[k * H + f], r);
    }
    s_uv[f][grp] = bf16r(u) | (bf16r(v) << 16);
    s_r[f][grp]  = r;
    __syncthreads();
    int fo = threadIdx.x >> 3;
    int nl = threadIdx.x & 7;
    UVs[(size_t)fo * N_ + base8 + nl] = s_uv[fo][nl];
    Rs [(size_t)fo * N_ + base8 + nl] = s_r [fo][nl];
}

// ---------------- LDS-sliced conv aggregation, 1024-thread blocks ----------------
// block = (slice s, 640-node chunk). LDS = full per-feature UV table (40 KB).
// 16 waves x (8 nodes x 8 slots); always-6 slot groups (no maxd shfl chain);
// rare deep-node tail via vcc __any.

__global__ __launch_bounds__(1024, 8) void k_agg_lds(
        const int* __restrict__ counts, const unsigned* __restrict__ meta2,
        const unsigned* __restrict__ UVs, const float* __restrict__ Rs,
        float* __restrict__ Hs) {
    __shared__ __align__(16) unsigned uvl[N_];
    int s     = blockIdx.x & 31;
    int chunk = blockIdx.x >> 5;

    int l   = threadIdx.x & 63;
    int wav = threadIdx.x >> 6;      // 0..15
    int j0  = l & 7;                 // slot within group
    int nl  = l >> 3;                // node within wave (0..7)

    // ---- initial prefetch (overlaps LDS fill) ----
    int cbase = chunk * TILE + wav * 8;
    int node = cbase + nl;
    int nc = min(node, N_ - 1);
    int dg = (node < N_) ? counts[nc] : 0;
    float rv = Rs[(size_t)s * N_ + nc];
    const unsigned* mrow = meta2 + (size_t)(cbase >> 3) * ROW + l;
    unsigned m0 = mrow[0], m1 = mrow[64], m2 = mrow[128],
             m3 = mrow[192], m4 = mrow[256], m5 = mrow[320];

    // ---- fill LDS with this slice's UV table (coalesced 40 KB, 3 sweeps) ----
    const unsigned* srcp = UVs + (size_t)s * N_;
    #pragma unroll
    for (int i = 0; i < 3; ++i) {
        int d4 = (i * AT + (int)threadIdx.x) * 4;
        if (d4 + 4 <= N_) {
            uint4 t = *reinterpret_cast<const uint4*>(srcp + d4);
            *reinterpret_cast<uint4*>(&uvl[d4]) = t;
        }
    }
    __syncthreads();

    for (int it = 0; it < ITERS; ++it) {
        // ---- prefetch next group (128 nodes ahead) ----
        int nbase = cbase + 128;
        int nnode = nbase + nl;
        int nnc = min(nnode, N_ - 1);
        int ndg = 0; float nrv = 0.f;
        unsigned n0 = 0, n1 = 0, n2 = 0, n3 = 0, n4 = 0, n5 = 0;
        if (it < ITERS - 1) {
            ndg = (nnode < N_) ? counts[nnc] : 0;
            nrv = Rs[(size_t)s * N_ + nnc];
            const unsigned* nmr = meta2 + (size_t)(nbase >> 3) * ROW + l;
            n0 = nmr[0]; n1 = nmr[64]; n2 = nmr[128];
            n3 = nmr[192]; n4 = nmr[256]; n5 = nmr[320];
        }

        // ---- compute current group: always 6 slot groups (48 slots) ----
        float acc = 0.f;
        auto slot = [&](int p, unsigned mv) {
            unsigned idx = min(mv & 0xFFFFu, (unsigned)(N_ - 1));
            unsigned w = uvl[idx];
            float t = fmaf(__uint_as_float(mv & 0xFFFF0000u),   // a (bf16 hi)
                           __uint_as_float(w << 16),            // u
                           __uint_as_float(w & 0xFFFF0000u));   // v
            if (j0 + 8 * p < dg) acc += t;
        };
        slot(0, m0); slot(1, m1); slot(2, m2);
        slot(3, m3); slot(4, m4); slot(5, m5);
        if (__any(dg > 48)) {                  // rare deep-node tail (~2% of waves)
            const unsigned* trow = meta2 + (size_t)(cbase >> 3) * ROW + l;
            for (int p = 6; __any(j0 + 8 * p < dg); ++p)
                slot(p, trow[p * 64]);
        }
        acc += __shfl_xor(acc, 1);
        acc += __shfl_xor(acc, 2);
        acc += __shfl_xor(acc, 4);
        float h = fmaxf(rv + acc, 0.f);
        if (j0 == 0 && node < N_) Hs[(size_t)s * N_ + node] = h;

        cbase = nbase; node = nnode; nc = nnc; dg = ndg; rv = nrv;
        m0 = n0; m1 = n1; m2 = n2; m3 = n3; m4 = n4; m5 = n5;
    }
}

// ---------------- per-graph pooling + readout: 64 independent blocks, NO atomics ----------

__global__ __launch_bounds__(256) void k_pool(
        const float* __restrict__ Hs, const int* __restrict__ startsP,
        const float* __restrict__ w1, const float* __restrict__ b1,
        const float* __restrict__ w2, const float* __restrict__ b2,
        float* __restrict__ out) {
    __shared__ int sst[G];
    __shared__ float ga[32], gm[32], gx[32];
    int tid = threadIdx.x;
    if (tid < G) sst[tid] = startsP[tid];
    __syncthreads();
    int g = blockIdx.x;
    int sp = sst[g];
    int s = 0, e = 0;
    if (sp != 0) {
        s = sp - 1;
        e = N_;
        for (int j = g + 1; j < G; ++j)
            if (sst[j]) { e = sst[j] - 1; break; }
    }
    int f = tid >> 3, oct = tid & 7;
    float sum = 0.f, mx = 0.f;
    for (int n = s + oct; n < e; n += 8) {
        float w = Hs[(size_t)f * N_ + n];
        sum += w;
        mx = fmaxf(mx, w);
    }
    sum += __shfl_xor(sum, 1); mx = fmaxf(mx, __shfl_xor(mx, 1));
    sum += __shfl_xor(sum, 2); mx = fmaxf(mx, __shfl_xor(mx, 2));
    sum += __shfl_xor(sum, 4); mx = fmaxf(mx, __shfl_xor(mx, 4));
    if (oct == 0) {
        float c = fmaxf((float)(e - s), 1.0f);
        ga[f] = sum;
        gm[f] = sum / c;
        gx[f] = mx;
    }
    __syncthreads();
    if (tid < 32) {
        float hacc = b1[tid];
        #pragma unroll
        for (int k = 0; k < H; ++k) {
            hacc = fmaf(ga[k], w1[k * H + tid], hacc);
            hacc = fmaf(gm[k], w1[(H + k) * H + tid], hacc);
            hacc = fmaf(gx[k], w1[(2 * H + k) * H + tid], hacc);
        }
        float hid = fmaxf(hacc, 0.f);
        float p0 = hid * w2[tid * 2 + 0];
        float p1 = hid * w2[tid * 2 + 1];
        #pragma unroll
        for (int offq = 16; offq; offq >>= 1) {
            p0 += __shfl_xor(p0, offq, 32);
            p1 += __shfl_xor(p1, offq, 32);
        }
        if (tid == 0) {
            float l0 = p0 + b2[0], l1 = p1 + b2[1];
            float m = fmaxf(l0, l1);
            float lse = m + logf(expf(l0 - m) + expf(l1 - m));
            out[g * 2 + 0] = l0 - lse;
            out[g * 2 + 1] = l1 - lse;
        }
    }
}

// ---------------- launch ----------------

extern "C" void kernel_launch(void* const* d_in, const int* in_sizes, int n_in,
                              void* d_out, int out_size, void* d_ws, size_t ws_size,
                              hipStream_t stream) {
    const float* x      = (const float*)d_in[0];
    const int*   ei     = (const int*)  d_in[1];
    const float* ea     = (const float*)d_in[2];
    const int*   batch  = (const int*)  d_in[3];
    const float* nn_w1  = (const float*)d_in[4];
    const float* nn_b1  = (const float*)d_in[5];
    const float* root1  = (const float*)d_in[6];
    const float* bias1  = (const float*)d_in[7];
    const float* nn_w2  = (const float*)d_in[8];
    const float* nn_b2  = (const float*)d_in[9];
    const float* root2  = (const float*)d_in[10];
    const float* bias2  = (const float*)d_in[11];
    const float* nn_w3  = (const float*)d_in[12];
    const float* nn_b3  = (const float*)d_in[13];
    const float* root3  = (const float*)d_in[14];
    const float* bias3  = (const float*)d_in[15];
    const float* lin1_w = (const float*)d_in[16];
    const float* lin1_b = (const float*)d_in[17];
    const float* lin2_w = (const float*)d_in[18];
    const float* lin2_b = (const float*)d_in[19];
    float* out = (float*)d_out;

    char* ws = (char*)d_ws;
    size_t off = 0;
    auto alloc = [&](size_t bytes) -> void* {
        void* p = ws + off;
        off += (bytes + 255) & ~(size_t)255;
        return p;
    };
    // zero-init chunk: counts | startsP
    const size_t zbytes = N_ * sizeof(int) + G * sizeof(int);
    char* zchunk = (char*)alloc(zbytes);
    int*  counts  = (int*)zchunk;
    int*  startsP = (int*)(zchunk + N_ * sizeof(int));
    unsigned* meta2 = (unsigned*)alloc((size_t)NB_ * ROW * sizeof(unsigned)); // 3.93 MB
    unsigned* UVs1 = (unsigned*)alloc((size_t)H * N_ * sizeof(unsigned));
    unsigned* UVs2 = (unsigned*)alloc((size_t)H * N_ * sizeof(unsigned));
    unsigned* UVs3 = (unsigned*)alloc((size_t)H * N_ * sizeof(unsigned));
    float* Rs1 = (float*)alloc((size_t)H * N_ * sizeof(float));
    float* Rs2 = (float*)alloc((size_t)H * N_ * sizeof(float));
    float* Rs3 = (float*)alloc((size_t)H * N_ * sizeof(float));
    float* h1  = (float*)alloc((size_t)H * N_ * sizeof(float));   // slice-major
    float* h2  = (float*)alloc((size_t)H * N_ * sizeof(float));
    float* h3  = (float*)alloc((size_t)H * N_ * sizeof(float));

    hipMemsetAsync(zchunk, 0, zbytes, stream);

    k_build_pre1<<<EBLK + PBLK, 256, 0, stream>>>(ei, ea, x, batch,
                                                  nn_w1, nn_b1, root1, bias1,
                                                  counts, meta2, UVs1, Rs1, startsP);

    k_agg_lds<<<SLICES * CHUNKS, AT, 0, stream>>>(counts, meta2, UVs1, Rs1, h1);
    k_pre    <<<PBLK, 256, 0, stream>>>(h1, nn_w2, nn_b2, root2, bias2, UVs2, Rs2);
    k_agg_lds<<<SLICES * CHUNKS, AT, 0, stream>>>(counts, meta2, UVs2, Rs2, h2);
    k_pre    <<<PBLK, 256, 0, stream>>>(h2, nn_w3, nn_b3, root3, bias3, UVs3, Rs3);
    k_agg_lds<<<SLICES * CHUNKS, AT, 0, stream>>>(counts, meta2, UVs3, Rs3, h3);

    k_pool<<<G, 256, 0, stream>>>(h3, startsP, lin1_w, lin1_b, lin2_w, lin2_b, out);
}